// Round 4
// baseline (19.132 us; speedup 1.0000x reference)
//
#include <hip/hip_runtime.h>
#include <hip/hip_bf16.h>
#include <math.h>

#define B_ 128
#define S_ 512
#define E_ 64
#define PAD_ 72  // bf16/row in LDS; 36-dword stride => 16B accesses tile 32 banks

typedef short bf16x8 __attribute__((ext_vector_type(8)));
typedef float f32x4 __attribute__((ext_vector_type(4)));

__device__ __forceinline__ unsigned short f2b(float f) {
  __hip_bfloat16 h = __float2bfloat16(f);  // compiler lowers pairs to v_cvt_pk_bf16_f32
  unsigned short u;
  __builtin_memcpy(&u, &h, 2);
  return u;
}

// Lane holds 16 contiguous elems of one row. Sum-sq: 16 FMA + shfl_xor(16,32)
// (reduce over the 4 g-lanes sharing the row). Store: 2x ds_write_b128.
__device__ __forceinline__ void norm_store(const f32x4 x[4], float scl_num,
                                           unsigned short* dst) {
  float ss = 0.f;
#pragma unroll
  for (int i = 0; i < 4; ++i)
#pragma unroll
    for (int j = 0; j < 4; ++j) ss = fmaf(x[i][j], x[i][j], ss);
  ss += __shfl_xor(ss, 16);
  ss += __shfl_xor(ss, 32);
  float s = scl_num / fmaxf(sqrtf(ss), 1e-7f);
  bf16x8 o0, o1;
#pragma unroll
  for (int i = 0; i < 2; ++i)
#pragma unroll
    for (int j = 0; j < 4; ++j) {
      o0[i * 4 + j] = (short)f2b(x[i][j] * s);
      o1[i * 4 + j] = (short)f2b(x[i + 2][j] * s);
    }
  *(bf16x8*)dst = o0;
  *(bf16x8*)(dst + 8) = o1;
}

// One block (1024 thr, 16 waves) per (batch, s-half). Phase 1: normalize V
// (fold w*cw) and U into LDS bf16. Phase 2: wave (ws,wn) = 64 s x 128 n MFMA
// max-scan; mask folded into the MFMA C-operand as a -1e30 penalty.
__global__ __launch_bounds__(1024) void fused_kernel(
    const float* __restrict__ ue, const float* __restrict__ ve,
    const float* __restrict__ cw, const float* __restrict__ mask,
    const float* __restrict__ pw, const float* __restrict__ pb,
    float* __restrict__ out) {
  __shared__ unsigned short vlds[S_ * PAD_];   // 73728 B
  __shared__ unsigned short ulds[256 * PAD_];  // 36864 B
  __shared__ float comb[4][256];               // 4096 B

  // XCD pair-swizzle: both s-halves of a batch land on the same XCD.
  const int bx = blockIdx.x;
  const int b = (bx & 7) * 16 + (bx >> 4);
  const int shalf = (bx >> 3) & 1;

  const int tid = threadIdx.x;
  const int wv = tid >> 6;
  const int lane = tid & 63;
  const int c = lane & 15;  // row-within-16 / MFMA col class
  const int g = lane >> 4;  // 16-elem column chunk / k-group
  const int ws = wv >> 2;   // s-split (0..3): 64 s-rows
  const int wn = wv & 3;    // n-split (0..3): 128 n

  const float w0 = pw[0];
  const float* __restrict__ vb = ve + (size_t)b * S_ * E_;
  const float* __restrict__ cwb = cw + (size_t)b * S_;
  const float* __restrict__ ub = ue + ((size_t)b * S_ + shalf * 256) * E_;
  const float* __restrict__ mb = mask + (size_t)b * S_;

  // ---- Stage ALL phase-1 loads up front ----
  const int vr0 = wv * 32 + c, vr1 = vr0 + 16, ur = wv * 16 + c;
  const f32x4* pv0 = (const f32x4*)(vb + (size_t)vr0 * E_ + g * 16);
  const f32x4* pv1 = (const f32x4*)(vb + (size_t)vr1 * E_ + g * 16);
  const f32x4* pu = (const f32x4*)(ub + (size_t)ur * E_ + g * 16);
  f32x4 xv0[4], xv1[4], xu[4];
#pragma unroll
  for (int i = 0; i < 4; ++i) {
    xv0[i] = pv0[i];
    xv1[i] = pv1[i];
    xu[i] = pu[i];
  }
  float cw0 = cwb[vr0] * w0;
  float cw1 = cwb[vr1] * w0;
  float pen[8];  // per-lane column penalty for this wave's 8 n-tiles
#pragma unroll
  for (int j = 0; j < 8; ++j)
    pen[j] = (mb[(wn * 8 + j) * 16 + c] > 0.5f) ? 0.0f : -1e30f;

  // ---- Normalize + emit bf16 to LDS ----
  norm_store(xv0, cw0, vlds + (size_t)vr0 * PAD_ + g * 16);
  norm_store(xv1, cw1, vlds + (size_t)vr1 * PAD_ + g * 16);
  norm_store(xu, 1.0f, ulds + (size_t)ur * PAD_ + g * 16);

  __syncthreads();

  // ---- Phase 2: A-fragments for 4 s-tiles (rows ws*64 + st*16 + c) ----
  const unsigned short* urp = ulds + (size_t)(ws * 64 + c) * PAD_ + g * 8;
  bf16x8 a[4][2];
#pragma unroll
  for (int st = 0; st < 4; ++st) {
    a[st][0] = *(const bf16x8*)(urp + st * 16 * PAD_);
    a[st][1] = *(const bf16x8*)(urp + st * 16 * PAD_ + 32);
  }

  float r[4][4];
#pragma unroll
  for (int st = 0; st < 4; ++st)
#pragma unroll
    for (int i = 0; i < 4; ++i) r[st][i] = -INFINITY;

#pragma unroll
  for (int j = 0; j < 8; ++j) {
    int it = wn * 8 + j;
    const unsigned short* vr = vlds + (size_t)(it * 16 + c) * PAD_ + g * 8;
    bf16x8 b0 = *(const bf16x8*)(vr);
    bf16x8 b1 = *(const bf16x8*)(vr + 32);
    f32x4 ci = {pen[j], pen[j], pen[j], pen[j]};
#pragma unroll
    for (int st = 0; st < 4; ++st) {
      f32x4 acc = __builtin_amdgcn_mfma_f32_16x16x32_bf16(a[st][0], b0, ci, 0, 0, 0);
      acc = __builtin_amdgcn_mfma_f32_16x16x32_bf16(a[st][1], b1, acc, 0, 0, 0);
      r[st][0] = fmaxf(r[st][0], acc[0]);
      r[st][1] = fmaxf(r[st][1], acc[1]);
      r[st][2] = fmaxf(r[st][2], acc[2]);
      r[st][3] = fmaxf(r[st][3], acc[3]);
    }
  }

  // ---- Reduce over the 16 column-lanes (xor 1,2,4,8 stays in kg group) ----
#pragma unroll
  for (int st = 0; st < 4; ++st)
#pragma unroll
    for (int i = 0; i < 4; ++i) {
      float v = r[st][i];
      v = fmaxf(v, __shfl_xor(v, 1)); v = fmaxf(v, __shfl_xor(v, 2));
      v = fmaxf(v, __shfl_xor(v, 4)); v = fmaxf(v, __shfl_xor(v, 8));
      r[st][i] = v;
    }

  if (c == 0) {
#pragma unroll
    for (int st = 0; st < 4; ++st)
#pragma unroll
      for (int i = 0; i < 4; ++i)
        comb[wn][ws * 64 + st * 16 + g * 4 + i] = r[st][i];
  }

  __syncthreads();

  // ---- Final: n-split combine + sigmoid, 256 outputs ----
  if (tid < 256) {
    float v = fmaxf(fmaxf(comb[0][tid], comb[1][tid]),
                    fmaxf(comb[2][tid], comb[3][tid]));
    float bias = pb[0];
    out[(size_t)b * S_ + shalf * 256 + tid] =
        (v < -1e29f) ? 0.0f : 1.0f / (1.0f + expf(-(v + bias)));
  }
}

extern "C" void kernel_launch(void* const* d_in, const int* in_sizes, int n_in,
                              void* d_out, int out_size, void* d_ws, size_t ws_size,
                              hipStream_t stream) {
  const float* ue = (const float*)d_in[0];
  const float* ve = (const float*)d_in[1];
  const float* cw = (const float*)d_in[2];
  const float* mask = (const float*)d_in[3];
  const float* pw = (const float*)d_in[4];
  const float* pb = (const float*)d_in[5];
  float* out = (float*)d_out;

  hipLaunchKernelGGL(fused_kernel, dim3(2 * B_), dim3(1024), 0, stream,
                     ue, ve, cw, mask, pw, pb, out);
}